// Round 9
// baseline (108.171 us; speedup 1.0000x reference)
//
#include <hip/hip_runtime.h>

#define B_  16
#define S_  512
#define H_  768
#define T_  9
#define HD_ 64
#define N1  (T_*HD_*2)   // 1152
#define M1  (B_*S_)      // 8192
#define NT1 (H_/32)      // 24 K-tiles

typedef __attribute__((ext_vector_type(8))) short bf16x8;
typedef __attribute__((ext_vector_type(4))) float f32x4;

#define GLB(p) ((const __attribute__((address_space(1))) void*)(p))
#define LDSP(p) ((__attribute__((address_space(3))) void*)(p))

__device__ inline unsigned short f2bf(float f){
  union { float f; unsigned u; } v; v.f = f;
  unsigned r = v.u + 0x7fffu + ((v.u >> 16) & 1u);   // RNE
  return (unsigned short)(r >> 16);
}

// --- prep: W [768,1152] fp32 -> Wt [1152,768] bf16 transpose | trig table ---
__global__ __launch_bounds__(256) void prep_wt(
    const float* __restrict__ W, short* __restrict__ Wt, float2* __restrict__ tab)
{
  __shared__ float tile[32][33];
  const int bx = blockIdx.x, tid = threadIdx.x;
  if(bx < 864){                       // 36 x 24 tiles of 32x32
    int n0 = (bx % 36)*32, k0 = (bx / 36)*32;
    int tx = tid & 31, ty = tid >> 5;
    #pragma unroll
    for(int r = 0; r < 32; r += 8)
      tile[ty + r][tx] = W[(size_t)(k0 + ty + r)*N1 + n0 + tx];
    __syncthreads();
    #pragma unroll
    for(int r = 0; r < 32; r += 8)
      Wt[(size_t)(n0 + ty + r)*H_ + k0 + tx] = (short)f2bf(tile[tx][ty + r]);
  } else {                            // 64 blocks: 512 x 32 trig entries
    int i = (bx - 864)*256 + tid;
    int s = i >> 5, p = i & 31;
    float inv = powf(10000.f, -2.f*(float)p/64.f);
    float a = (float)s * inv;
    tab[i] = make_float2(cosf(a), sinf(a));
  }
}

// --- GEMM1: BM=64 BN=64 BK=32 high-occupancy (2304 blocks, ~6/CU resident).
// Fused fp32->bf16 A reg-staging; 1-deep prefetch; 1 barrier per K-step. ---
__global__ __launch_bounds__(256, 6) void gemm1_rope(
    const float* __restrict__ hs, const short* __restrict__ Wt,
    const float* __restrict__ bias, const float2* __restrict__ tab,
    short* __restrict__ Qr, short* __restrict__ Kr)
{
  __shared__ short As[2][64*32];      // 2 x 4 KB
  __shared__ short Bs[2][64*32];      // 2 x 4 KB
  const int tid  = threadIdx.x;
  const int lane = tid & 63, w = tid >> 6;
  const int lr = lane & 15, h = lane >> 4;
  const int lk = h * 8;
  const int wm = (w & 1) * 32, wn = (w >> 1) * 32;
  const int n0 = blockIdx.x * 64;     // 18 n-tiles
  const int m0 = blockIdx.y * 64;     // 128 m-tiles

  // staging map: thread -> row tid>>2 (0..63), k-chunk (tid&3)*8
  const float* aS = hs + (size_t)(m0 + (tid >> 2)) * H_ + (tid & 3) * 8;
  const short* bS = Wt + (size_t)(n0 + (tid >> 2)) * H_ + (tid & 3) * 8;
  const int dOff = tid * 8;           // LDS shorts: [row][k] rows of 32

  f32x4 acc[2][2] = {};
  float4 ra0, ra1;

#define LOAD_A(k0) do{ ra0 = *(const float4*)(aS + (k0)); \
                       ra1 = *(const float4*)(aS + (k0) + 4); }while(0)
#define CVT_DSWRITE(buf) do{ \
    bf16x8 t_; \
    t_[0]=f2bf(ra0.x); t_[1]=f2bf(ra0.y); t_[2]=f2bf(ra0.z); t_[3]=f2bf(ra0.w); \
    t_[4]=f2bf(ra1.x); t_[5]=f2bf(ra1.y); t_[6]=f2bf(ra1.z); t_[7]=f2bf(ra1.w); \
    *(bf16x8*)(&As[buf][dOff]) = t_; \
  }while(0)
#define STAGE_B(buf, k0) \
    __builtin_amdgcn_global_load_lds(GLB(bS + (k0)), LDSP(&Bs[buf][dOff]), 16, 0, 0)

  // prologue: tile0 staged; A(1) in regs
  LOAD_A(0);
  CVT_DSWRITE(0);
  STAGE_B(0, 0);
  LOAD_A(32);

  for(int k = 0; k < NT1; ++k){
    __syncthreads();                  // implicit vmcnt(0)+lgkmcnt(0): buf[cur] ready
    const int cur = k & 1;
    if(k + 1 < NT1){
      CVT_DSWRITE(cur ^ 1);           // A(k+1) regs -> LDS
      STAGE_B(cur ^ 1, (k + 1) * 32);
    }
    if(k + 2 < NT1) LOAD_A((k + 2) * 32);   // keep one A-load of slack in flight

    bf16x8 aF[2], bF[2];
    #pragma unroll
    for(int i = 0; i < 2; ++i) aF[i] = *(const bf16x8*)(&As[cur][(wm + i*16 + lr)*32 + lk]);
    #pragma unroll
    for(int j = 0; j < 2; ++j) bF[j] = *(const bf16x8*)(&Bs[cur][(wn + j*16 + lr)*32 + lk]);
    #pragma unroll
    for(int i = 0; i < 2; ++i)
      #pragma unroll
      for(int j = 0; j < 2; ++j)
        acc[i][j] = __builtin_amdgcn_mfma_f32_16x16x32_bf16(bF[j], aF[i], acc[i][j], 0, 0, 0);
  }

  // epilogue: bias + lane-local RoPE + packed 4B stores (regs = 4 consecutive n)
  const int t = n0 >> 7;              // 64-wide n-tile sits inside one entity type
  #pragma unroll
  for(int i = 0; i < 2; ++i){
    int m  = m0 + wm + i*16 + lr;
    int bi = m >> 9, sp = m & 511;
    size_t rowoff = ((size_t)(bi*T_ + t)*S_ + sp)*HD_;
    #pragma unroll
    for(int j = 0; j < 2; ++j){
      int nq  = n0 + wn + j*16 + (h << 2);
      int hd0 = (nq >> 1) & 63;
      int p   = (nq >> 2) & 31;
      float4 bv = *(const float4*)(bias + nq);
      float2 cs = tab[sp*32 + p];
      float q0 = acc[i][j][0] + bv.x;
      float k0v= acc[i][j][1] + bv.y;
      float q1 = acc[i][j][2] + bv.z;
      float k1v= acc[i][j][3] + bv.w;
      float rq0 = q0*cs.x - q1*cs.y, rq1 = q1*cs.x + q0*cs.y;
      float rk0 = k0v*cs.x - k1v*cs.y, rk1 = k1v*cs.x + k0v*cs.y;
      unsigned uq = (unsigned)f2bf(rq0) | ((unsigned)f2bf(rq1) << 16);
      unsigned uk = (unsigned)f2bf(rk0) | ((unsigned)f2bf(rk1) << 16);
      *(unsigned*)(Qr + rowoff + hd0) = uq;
      *(unsigned*)(Kr + rowoff + hd0) = uk;
    }
  }
#undef LOAD_A
#undef CVT_DSWRITE
#undef STAGE_B
}

// --- biaffine (swapped operands): lane holds 4 consecutive n -> float4 store ---
__global__ __launch_bounds__(256) void gemm2_mask(
    const short* __restrict__ Qr, const short* __restrict__ Kr,
    const int* __restrict__ am, float* __restrict__ out)
{
  const int lane = threadIdx.x & 63;
  const int w    = threadIdx.x >> 6;
  const int bt   = blockIdx.z;
  const int b    = bt / T_;
  const int n0   = blockIdx.x * 128 + (w & 1) * 64;
  const int m0   = blockIdx.y * 128 + (w >> 1) * 64;
  const int lr   = lane & 15;
  const int lk   = (lane >> 4) * 8;

  const short* Q = Qr + (size_t)bt * S_ * HD_;
  const short* K = Kr + (size_t)bt * S_ * HD_;
  f32x4 acc[4][4] = {};

  #pragma unroll
  for(int ks = 0; ks < HD_; ks += 32){
    bf16x8 aF[4], bF[4];
    #pragma unroll
    for(int i = 0; i < 4; ++i) aF[i] = *(const bf16x8*)(Q + (size_t)(m0 + i*16 + lr)*HD_ + ks + lk);
    #pragma unroll
    for(int j = 0; j < 4; ++j) bF[j] = *(const bf16x8*)(K + (size_t)(n0 + j*16 + lr)*HD_ + ks + lk);
    #pragma unroll
    for(int i = 0; i < 4; ++i)
      #pragma unroll
      for(int j = 0; j < 4; ++j)
        acc[i][j] = __builtin_amdgcn_mfma_f32_16x16x32_bf16(bF[j], aF[i], acc[i][j], 0, 0, 0);
  }

  const int* amb = am + b * S_;
  #pragma unroll
  for(int i = 0; i < 4; ++i){
    int m = m0 + i*16 + lr;
    float amm = (float)amb[m];
    float* orow = out + ((size_t)bt*S_ + m)*S_;
    #pragma unroll
    for(int j = 0; j < 4; ++j){
      int nq = n0 + j*16 + ((lane >> 4) << 2);
      int4 a4 = *(const int4*)(amb + nq);
      float4 r;
      r.x = acc[i][j][0]*0.125f - (1.f - amm*(float)a4.x)*1e12f - ((nq+0) < m ? 1e12f : 0.f);
      r.y = acc[i][j][1]*0.125f - (1.f - amm*(float)a4.y)*1e12f - ((nq+1) < m ? 1e12f : 0.f);
      r.z = acc[i][j][2]*0.125f - (1.f - amm*(float)a4.z)*1e12f - ((nq+2) < m ? 1e12f : 0.f);
      r.w = acc[i][j][3]*0.125f - (1.f - amm*(float)a4.w)*1e12f - ((nq+3) < m ? 1e12f : 0.f);
      *(float4*)(orow + nq) = r;
    }
  }
}

extern "C" void kernel_launch(void* const* d_in, const int* in_sizes, int n_in,
                              void* d_out, int out_size, void* d_ws, size_t ws_size,
                              hipStream_t stream)
{
  const float* hs    = (const float*)d_in[0];
  const int*   amask = (const int*)  d_in[1];
  const float* W     = (const float*)d_in[2];
  const float* bias  = (const float*)d_in[3];
  float* out = (float*)d_out;

  char* ws = (char*)d_ws;
  short*  Wt  = (short*) (ws);                       // 1,769,472 B
  float2* tab = (float2*)(ws + 1769472);             //   131,072 B
  short*  Qr  = (short*) (ws + 1900544);             // 9,437,184 B
  short*  Kr  = (short*) (ws + 11337728);            // 9,437,184 B

  prep_wt   <<<928, 256, 0, stream>>>(W, Wt, tab);
  gemm1_rope<<<dim3(N1/64, M1/64), 256, 0, stream>>>(hs, Wt, bias, tab, Qr, Kr);
  gemm2_mask<<<dim3(S_/128, S_/128, B_*T_), 256, 0, stream>>>(Qr, Kr, amask, out);
}

// Round 10
// 98.433 us; speedup vs baseline: 1.0989x; 1.0989x over previous
//
#include <hip/hip_runtime.h>

#define B_  16
#define S_  512
#define H_  768
#define T_  9
#define HD_ 64
#define N1  (T_*HD_*2)   // 1152
#define M1  (B_*S_)      // 8192
#define NT1 (H_/64)      // 12 K-tiles of 64

typedef __attribute__((ext_vector_type(8))) short bf16x8;
typedef __attribute__((ext_vector_type(4))) float f32x4;

#define GLB(p) ((const __attribute__((address_space(1))) void*)(p))
#define LDSP(p) ((__attribute__((address_space(3))) void*)(p))

__device__ inline unsigned short f2bf(float f){
  union { float f; unsigned u; } v; v.f = f;
  unsigned r = v.u + 0x7fffu + ((v.u >> 16) & 1u);   // RNE
  return (unsigned short)(r >> 16);
}

// Swizzle-at-rest: element (row, k) stored at k' = k XOR ((row&7)<<3) within
// each 64-elem k-window (bijective). global_load_lds stages rows linearly;
// fragment reads apply the same XOR -> 2-way banks (free) at BK=64.

// --- merged prep: hs->Abf (swizzled) | W->Wt (transpose+swizzled) | trig ---
__global__ __launch_bounds__(256) void prep_all(
    const float* __restrict__ hs, short* __restrict__ Abf,
    const float* __restrict__ W, short* __restrict__ Wt,
    float2* __restrict__ tab)
{
  __shared__ float tile[32][33];
  const int bx = blockIdx.x, tid = threadIdx.x;
  if(bx < 3072){
    int i = bx*2048 + tid*8;            // 8 consecutive k of one row
    int row = i / H_, k = i % H_;
    float4 a0 = *(const float4*)(hs + i);
    float4 a1 = *(const float4*)(hs + i + 4);
    bf16x8 r;
    r[0]=f2bf(a0.x); r[1]=f2bf(a0.y); r[2]=f2bf(a0.z); r[3]=f2bf(a0.w);
    r[4]=f2bf(a1.x); r[5]=f2bf(a1.y); r[6]=f2bf(a1.z); r[7]=f2bf(a1.w);
    int kk = (k & ~63) | ((k ^ ((row & 7) << 3)) & 63);
    *(bf16x8*)(Abf + (size_t)row*H_ + kk) = r;
  } else if(bx < 3936){
    int idx = bx - 3072;
    int n0 = (idx % 36)*32, k0 = (idx / 36)*32;
    int tx = tid & 31, ty = tid >> 5;
    #pragma unroll
    for(int r = 0; r < 32; r += 8)
      tile[ty + r][tx] = W[(size_t)(k0 + ty + r)*N1 + n0 + tx];
    __syncthreads();
    #pragma unroll
    for(int r = 0; r < 32; r += 8){
      int n = n0 + ty + r, k = k0 + tx;
      int kk = (k & ~63) | ((k ^ ((n & 7) << 3)) & 63);
      Wt[(size_t)n*H_ + kk] = (short)f2bf(tile[tx][ty + r]);
    }
  } else {
    int i = (bx - 3936)*256 + tid;      // 512 x 32 trig entries
    int s = i >> 5, p = i & 31;
    float inv = powf(10000.f, -2.f*(float)p/64.f);
    float a = (float)s * inv;
    tab[i] = make_float2(cosf(a), sinf(a));
  }
}

// --- GEMM1: 128x128, BK=64, 12 iters, 1 barrier/iter, 32 MFMA/wave/phase ---
__global__ __launch_bounds__(256, 2) void gemm1_rope(
    const short* __restrict__ Abf, const short* __restrict__ Wt,
    const float* __restrict__ bias, const float2* __restrict__ tab,
    short* __restrict__ Qr, short* __restrict__ Kr)
{
  __shared__ short As[2][128*64];     // 2 x 16 KB
  __shared__ short Bs[2][128*64];     // 2 x 16 KB
  const int tid  = threadIdx.x;
  const int lane = tid & 63, w = tid >> 6;
  const int lr = lane & 15, h = lane >> 4;
  const int wm = (w >> 1) * 64, wn = (w & 1) * 64;
  const int n0 = blockIdx.x * 128;    // 9 n-tiles (= entity type)
  const int m0 = blockIdx.y * 128;    // 64 m-tiles
  const int sw = (lr & 7) << 3;       // fragment-read XOR (elements)

  // staging map: thread -> row tid>>3 (0..31, x4 via q), 16B chunk tid&7
  const short* aS = Abf + (size_t)(m0 + (tid >> 3)) * H_ + (tid & 7) * 8;
  const short* bS = Wt  + (size_t)(n0 + (tid >> 3)) * H_ + (tid & 7) * 8;
  const int dOff = tid * 8;

#define STAGE(buf, k0) do{ \
    _Pragma("unroll") \
    for(int q = 0; q < 4; ++q){ \
      __builtin_amdgcn_global_load_lds(GLB(aS + (size_t)q*32*H_ + (k0)), \
                                       LDSP(&As[buf][q*2048 + dOff]), 16, 0, 0); \
      __builtin_amdgcn_global_load_lds(GLB(bS + (size_t)q*32*H_ + (k0)), \
                                       LDSP(&Bs[buf][q*2048 + dOff]), 16, 0, 0); \
    } \
  }while(0)

  f32x4 acc[4][4] = {};
  STAGE(0, 0);

  for(int it = 0; it < NT1; ++it){
    __syncthreads();                  // implicit vmcnt(0): tile(it) resident
    const int cur = it & 1;
    if(it + 1 < NT1) STAGE(cur ^ 1, (it + 1) * 64);   // flies during compute

    #pragma unroll
    for(int ks = 0; ks < 2; ++ks){
      const int kb = ks * 32;
      bf16x8 aF[4], bF[4];
      #pragma unroll
      for(int i = 0; i < 4; ++i)
        aF[i] = *(const bf16x8*)(&As[cur][(wm + i*16 + lr)*64 + ((kb + h*8) ^ sw)]);
      #pragma unroll
      for(int j = 0; j < 4; ++j)
        bF[j] = *(const bf16x8*)(&Bs[cur][(wn + j*16 + lr)*64 + ((kb + h*8) ^ sw)]);
      #pragma unroll
      for(int i = 0; i < 4; ++i)
        #pragma unroll
        for(int j = 0; j < 4; ++j)
          acc[i][j] = __builtin_amdgcn_mfma_f32_16x16x32_bf16(bF[j], aF[i], acc[i][j], 0, 0, 0);
    }
  }

  // epilogue: bias + lane-local RoPE + packed 4B stores (regs = 4 consecutive n)
  const int t = blockIdx.x;           // n-tile of 128 == one entity type
  #pragma unroll
  for(int i = 0; i < 4; ++i){
    int m  = m0 + wm + i*16 + lr;
    int bi = m >> 9, sp = m & 511;
    size_t rowoff = ((size_t)(bi*T_ + t)*S_ + sp)*HD_;
    #pragma unroll
    for(int j = 0; j < 4; ++j){
      int nq  = n0 + wn + j*16 + (h << 2);
      int hd0 = (nq >> 1) & 63;
      int p   = (nq >> 2) & 31;
      float4 bv = *(const float4*)(bias + nq);
      float2 cs = tab[sp*32 + p];
      float q0 = acc[i][j][0] + bv.x;
      float k0v= acc[i][j][1] + bv.y;
      float q1 = acc[i][j][2] + bv.z;
      float k1v= acc[i][j][3] + bv.w;
      float rq0 = q0*cs.x - q1*cs.y, rq1 = q1*cs.x + q0*cs.y;
      float rk0 = k0v*cs.x - k1v*cs.y, rk1 = k1v*cs.x + k0v*cs.y;
      unsigned uq = (unsigned)f2bf(rq0) | ((unsigned)f2bf(rq1) << 16);
      unsigned uk = (unsigned)f2bf(rk0) | ((unsigned)f2bf(rk1) << 16);
      *(unsigned*)(Qr + rowoff + hd0) = uq;
      *(unsigned*)(Kr + rowoff + hd0) = uk;
    }
  }
#undef STAGE
}

// --- biaffine (swapped operands): lane holds 4 consecutive n -> float4 store ---
__global__ __launch_bounds__(256) void gemm2_mask(
    const short* __restrict__ Qr, const short* __restrict__ Kr,
    const int* __restrict__ am, float* __restrict__ out)
{
  const int lane = threadIdx.x & 63;
  const int w    = threadIdx.x >> 6;
  const int bt   = blockIdx.z;
  const int b    = bt / T_;
  const int n0   = blockIdx.x * 128 + (w & 1) * 64;
  const int m0   = blockIdx.y * 128 + (w >> 1) * 64;
  const int lr   = lane & 15;
  const int lk   = (lane >> 4) * 8;

  const short* Q = Qr + (size_t)bt * S_ * HD_;
  const short* K = Kr + (size_t)bt * S_ * HD_;
  f32x4 acc[4][4] = {};

  #pragma unroll
  for(int ks = 0; ks < HD_; ks += 32){
    bf16x8 aF[4], bF[4];
    #pragma unroll
    for(int i = 0; i < 4; ++i) aF[i] = *(const bf16x8*)(Q + (size_t)(m0 + i*16 + lr)*HD_ + ks + lk);
    #pragma unroll
    for(int j = 0; j < 4; ++j) bF[j] = *(const bf16x8*)(K + (size_t)(n0 + j*16 + lr)*HD_ + ks + lk);
    #pragma unroll
    for(int i = 0; i < 4; ++i)
      #pragma unroll
      for(int j = 0; j < 4; ++j)
        acc[i][j] = __builtin_amdgcn_mfma_f32_16x16x32_bf16(bF[j], aF[i], acc[i][j], 0, 0, 0);
  }

  const int* amb = am + b * S_;
  #pragma unroll
  for(int i = 0; i < 4; ++i){
    int m = m0 + i*16 + lr;
    float amm = (float)amb[m];
    float* orow = out + ((size_t)bt*S_ + m)*S_;
    #pragma unroll
    for(int j = 0; j < 4; ++j){
      int nq = n0 + j*16 + ((lane >> 4) << 2);
      int4 a4 = *(const int4*)(amb + nq);
      float4 r;
      r.x = acc[i][j][0]*0.125f - (1.f - amm*(float)a4.x)*1e12f - ((nq+0) < m ? 1e12f : 0.f);
      r.y = acc[i][j][1]*0.125f - (1.f - amm*(float)a4.y)*1e12f - ((nq+1) < m ? 1e12f : 0.f);
      r.z = acc[i][j][2]*0.125f - (1.f - amm*(float)a4.z)*1e12f - ((nq+2) < m ? 1e12f : 0.f);
      r.w = acc[i][j][3]*0.125f - (1.f - amm*(float)a4.w)*1e12f - ((nq+3) < m ? 1e12f : 0.f);
      *(float4*)(orow + nq) = r;
    }
  }
}

extern "C" void kernel_launch(void* const* d_in, const int* in_sizes, int n_in,
                              void* d_out, int out_size, void* d_ws, size_t ws_size,
                              hipStream_t stream)
{
  const float* hs    = (const float*)d_in[0];
  const int*   amask = (const int*)  d_in[1];
  const float* W     = (const float*)d_in[2];
  const float* bias  = (const float*)d_in[3];
  float* out = (float*)d_out;

  char* ws = (char*)d_ws;
  short*  Wt  = (short*) (ws);                       // 1,769,472 B
  float2* tab = (float2*)(ws + 1769472);             //   131,072 B
  short*  Qr  = (short*) (ws + 1900544);             // 9,437,184 B
  short*  Kr  = (short*) (ws + 11337728);            // 9,437,184 B
  short*  Abf = (short*) (ws + 20774912);            // 12,582,912 B

  prep_all  <<<4000, 256, 0, stream>>>(hs, Abf, W, Wt, tab);
  gemm1_rope<<<dim3(N1/128, M1/128), 256, 0, stream>>>(Abf, Wt, bias, tab, Qr, Kr);
  gemm2_mask<<<dim3(S_/128, S_/128, B_*T_), 256, 0, stream>>>(Qr, Kr, amask, out);
}